// Round 1
// baseline (554.991 us; speedup 1.0000x reference)
//
#include <hip/hip_runtime.h>
#include <cmath>

#define C_DIM 128
#define S_DIM 4096
#define HW    176     // 16*11
#define B_SEG 32
#define O_DIM 256

// ---------------- Kernel 1: ragged segment max over S ----------------
// grid = B_SEG*C_DIM blocks, block = 192 threads (lanes 0..175 active).
// Each block handles (b, c): max over frames s in [s0, s0+len) of
// x[(c*S + s)*176 + e], writes pooled[(b*C + c)*176 + e].
__global__ __launch_bounds__(192) void seg_max_kernel(
    const float* __restrict__ x, const int* __restrict__ seqL,
    float* __restrict__ pooled)
{
    int bc = blockIdx.x;
    int c  = bc & (C_DIM - 1);
    int b  = bc >> 7;

    int s0 = 0;
    for (int i = 0; i < b; ++i) s0 += seqL[i];   // tiny, cached
    int len = seqL[b];

    int e = threadIdx.x;
    if (e >= HW) return;

    const float* xp = x + ((size_t)c * S_DIM + s0) * HW + e;
    float m = -INFINITY;
    int s = 0;
    for (; s + 4 <= len; s += 4) {
        float a0 = xp[(size_t)(s + 0) * HW];
        float a1 = xp[(size_t)(s + 1) * HW];
        float a2 = xp[(size_t)(s + 2) * HW];
        float a3 = xp[(size_t)(s + 3) * HW];
        m = fmaxf(m, fmaxf(fmaxf(a0, a1), fmaxf(a2, a3)));
    }
    for (; s < len; ++s) m = fmaxf(m, xp[(size_t)s * HW]);

    pooled[((size_t)b * C_DIM + c) * HW + e] = m;
}

// ---------------- Kernel 2: 1x1 conv + GeM, fused ----------------
// grid = 256 blocks: b = bx>>3, o-tile (32 wide) = bx&7.
// block = 128 threads: o_l = t&31, part = t>>5 (4 h-splits of 44 pos).
// Per thread: y[b, o, part*44 .. part*44+43] accumulated in registers,
// then GeM reduce -> out[b, o, part].
__global__ __launch_bounds__(128) void conv_gem_kernel(
    const float* __restrict__ pooled, const float* __restrict__ Wm,
    const float* __restrict__ p, float* __restrict__ out)
{
    int bx = blockIdx.x;
    int b  = bx >> 3;
    int ot = bx & 7;
    int t  = threadIdx.x;
    int o_l  = t & 31;
    int part = t >> 5;
    int o = ot * 32 + o_l;

    __shared__ __align__(16) float pl[32 * HW];  // pooled c-tile [32][176]
    __shared__ float wl[32 * 33];                // W tile [c][o], padded

    float acc[44];
#pragma unroll
    for (int j = 0; j < 44; ++j) acc[j] = 0.f;

    for (int c0 = 0; c0 < C_DIM; c0 += 32) {
        __syncthreads();
        // stage pooled[b, c0:c0+32, :] -- coalesced
        const float* src = pooled + ((size_t)b * C_DIM + c0) * HW;
        for (int i = t; i < 32 * HW; i += 128) pl[i] = src[i];
        // stage W[ot*32 .. +32, c0:c0+32] transposed, padded stride 33
        for (int i = t; i < 32 * 32; i += 128) {
            int oo = i >> 5;
            int cc = i & 31;
            wl[cc * 33 + oo] = Wm[(size_t)(ot * 32 + oo) * C_DIM + c0 + cc];
        }
        __syncthreads();

        float wreg[32];
#pragma unroll
        for (int cc = 0; cc < 32; ++cc) wreg[cc] = wl[cc * 33 + o_l];

#pragma unroll 4
        for (int cc = 0; cc < 32; ++cc) {
            const float4* p4 = (const float4*)(pl + cc * HW + part * 44);
            float w = wreg[cc];
#pragma unroll
            for (int j = 0; j < 11; ++j) {
                float4 v = p4[j];
                acc[4 * j + 0] = fmaf(v.x, w, acc[4 * j + 0]);
                acc[4 * j + 1] = fmaf(v.y, w, acc[4 * j + 1]);
                acc[4 * j + 2] = fmaf(v.z, w, acc[4 * j + 2]);
                acc[4 * j + 3] = fmaf(v.w, w, acc[4 * j + 3]);
            }
        }
    }

    // GeM: (mean(clip(v, eps)^pw))^(1/pw) over 44 positions
    float pw = p[part];
    float s = 0.f;
#pragma unroll
    for (int j = 0; j < 44; ++j) {
        float v = fmaxf(acc[j], 1e-6f);
        s += __expf(pw * __logf(v));
    }
    float g = __powf(s * (1.0f / 44.0f), 1.0f / pw);
    out[((size_t)b * O_DIM + o) * 4 + part] = g;
}

extern "C" void kernel_launch(void* const* d_in, const int* in_sizes, int n_in,
                              void* d_out, int out_size, void* d_ws, size_t ws_size,
                              hipStream_t stream)
{
    const float* x    = (const float*)d_in[0];   // [1,128,4096,16,11]
    const int*   seqL = (const int*)d_in[1];     // [32]
    const float* Wm   = (const float*)d_in[2];   // [256,128]
    const float* p    = (const float*)d_in[3];   // [4]
    float* out    = (float*)d_out;               // [32,256,4]
    float* pooled = (float*)d_ws;                // [32,128,176] = 2.88 MB

    seg_max_kernel<<<B_SEG * C_DIM, 192, 0, stream>>>(x, seqL, pooled);
    conv_gem_kernel<<<256, 128, 0, stream>>>(pooled, Wm, p, out);
}

// Round 2
// 547.722 us; speedup vs baseline: 1.0133x; 1.0133x over previous
//
#include <hip/hip_runtime.h>
#include <cmath>

#define C_DIM 128
#define S_DIM 4096
#define HW    176     // 16*11 floats per frame-row
#define HW4   44      // float4 per row
#define B_SEG 32
#define O_DIM 256

// ---------------- Kernel 1: ragged segment max over S (v2) ----------------
// grid = B_SEG*C_DIM = 4096 blocks, block = 512 threads = 8 waves.
// Block (b,c): wave w processes rows s = w, w+8, ... of the contiguous slab
// x[(c*S + s0)*176 ...], lanes 0..43 each load one float4 (full 704B row per
// wave-instr). 4-deep unroll -> ~22KB in flight per block. LDS max-reduce
// across the 8 waves at the end.
__global__ __launch_bounds__(512) void seg_max_kernel(
    const float* __restrict__ x, const int* __restrict__ seqL,
    float* __restrict__ pooled)
{
    int bc = blockIdx.x;
    int c  = bc & (C_DIM - 1);
    int b  = bc >> 7;

    __shared__ int sL[B_SEG];
    __shared__ __align__(16) float red[8][HW];

    int t = threadIdx.x;
    if (t < B_SEG) sL[t] = seqL[t];
    __syncthreads();

    int s0 = 0;
    for (int i = 0; i < b; ++i) s0 += sL[i];
    int len = sL[b];

    int w    = t >> 6;   // wave 0..7
    int lane = t & 63;

    float4 m = make_float4(-INFINITY, -INFINITY, -INFINITY, -INFINITY);

    if (lane < HW4) {
        const float4* xp = (const float4*)(x + ((size_t)c * S_DIM + s0) * HW);
        int s = w;
        // 4 rows (stride 8) in flight per lane
        for (; s + 24 < len; s += 32) {
            float4 a0 = xp[(size_t)(s     ) * HW4 + lane];
            float4 a1 = xp[(size_t)(s +  8) * HW4 + lane];
            float4 a2 = xp[(size_t)(s + 16) * HW4 + lane];
            float4 a3 = xp[(size_t)(s + 24) * HW4 + lane];
            m.x = fmaxf(m.x, fmaxf(fmaxf(a0.x, a1.x), fmaxf(a2.x, a3.x)));
            m.y = fmaxf(m.y, fmaxf(fmaxf(a0.y, a1.y), fmaxf(a2.y, a3.y)));
            m.z = fmaxf(m.z, fmaxf(fmaxf(a0.z, a1.z), fmaxf(a2.z, a3.z)));
            m.w = fmaxf(m.w, fmaxf(fmaxf(a0.w, a1.w), fmaxf(a2.w, a3.w)));
        }
        for (; s < len; s += 8) {
            float4 a = xp[(size_t)s * HW4 + lane];
            m.x = fmaxf(m.x, a.x);
            m.y = fmaxf(m.y, a.y);
            m.z = fmaxf(m.z, a.z);
            m.w = fmaxf(m.w, a.w);
        }
        ((float4*)red[w])[lane] = m;
    }
    __syncthreads();

    if (t < HW) {
        float r = red[0][t];
#pragma unroll
        for (int ww = 1; ww < 8; ++ww) r = fmaxf(r, red[ww][t]);
        pooled[((size_t)b * C_DIM + c) * HW + t] = r;
    }
}

// ---------------- Kernel 2: 1x1 conv + GeM, fused ----------------
// grid = 256 blocks: b = bx>>3, o-tile (32 wide) = bx&7.
// block = 128 threads: o_l = t&31, part = t>>5 (4 h-splits of 44 pos).
__global__ __launch_bounds__(128) void conv_gem_kernel(
    const float* __restrict__ pooled, const float* __restrict__ Wm,
    const float* __restrict__ p, float* __restrict__ out)
{
    int bx = blockIdx.x;
    int b  = bx >> 3;
    int ot = bx & 7;
    int t  = threadIdx.x;
    int o_l  = t & 31;
    int part = t >> 5;
    int o = ot * 32 + o_l;

    __shared__ __align__(16) float pl[32 * HW];  // pooled c-tile [32][176]
    __shared__ float wl[32 * 33];                // W tile [c][o], padded

    float acc[44];
#pragma unroll
    for (int j = 0; j < 44; ++j) acc[j] = 0.f;

    for (int c0 = 0; c0 < C_DIM; c0 += 32) {
        __syncthreads();
        const float* src = pooled + ((size_t)b * C_DIM + c0) * HW;
        for (int i = t; i < 32 * HW; i += 128) pl[i] = src[i];
        for (int i = t; i < 32 * 32; i += 128) {
            int oo = i >> 5;
            int cc = i & 31;
            wl[cc * 33 + oo] = Wm[(size_t)(ot * 32 + oo) * C_DIM + c0 + cc];
        }
        __syncthreads();

        float wreg[32];
#pragma unroll
        for (int cc = 0; cc < 32; ++cc) wreg[cc] = wl[cc * 33 + o_l];

#pragma unroll 4
        for (int cc = 0; cc < 32; ++cc) {
            const float4* p4 = (const float4*)(pl + cc * HW + part * 44);
            float w = wreg[cc];
#pragma unroll
            for (int j = 0; j < 11; ++j) {
                float4 v = p4[j];
                acc[4 * j + 0] = fmaf(v.x, w, acc[4 * j + 0]);
                acc[4 * j + 1] = fmaf(v.y, w, acc[4 * j + 1]);
                acc[4 * j + 2] = fmaf(v.z, w, acc[4 * j + 2]);
                acc[4 * j + 3] = fmaf(v.w, w, acc[4 * j + 3]);
            }
        }
    }

    float pw = p[part];
    float s = 0.f;
#pragma unroll
    for (int j = 0; j < 44; ++j) {
        float v = fmaxf(acc[j], 1e-6f);
        s += __expf(pw * __logf(v));
    }
    float g = __powf(s * (1.0f / 44.0f), 1.0f / pw);
    out[((size_t)b * O_DIM + o) * 4 + part] = g;
}

extern "C" void kernel_launch(void* const* d_in, const int* in_sizes, int n_in,
                              void* d_out, int out_size, void* d_ws, size_t ws_size,
                              hipStream_t stream)
{
    const float* x    = (const float*)d_in[0];   // [1,128,4096,16,11] fp32
    const int*   seqL = (const int*)d_in[1];     // [32]
    const float* Wm   = (const float*)d_in[2];   // [256,128]
    const float* p    = (const float*)d_in[3];   // [4]
    float* out    = (float*)d_out;               // [32,256,4]
    float* pooled = (float*)d_ws;                // [32,128,176] = 2.88 MB

    seg_max_kernel<<<B_SEG * C_DIM, 512, 0, stream>>>(x, seqL, pooled);
    conv_gem_kernel<<<256, 128, 0, stream>>>(pooled, Wm, p, out);
}